// Round 6
// baseline (754.532 us; speedup 1.0000x reference)
//
#include <hip/hip_runtime.h>
#include <hip/hip_bf16.h>
#include <math.h>

#define T_TOK 8192
#define DM 1024
#define DF 4096
#define NE 8
#define MAXT 144   // max 128-row tiles: 128 full + 7 partials + slack

typedef __attribute__((ext_vector_type(4))) float  f32x4;
typedef __attribute__((ext_vector_type(8))) short  s16x8;
typedef __attribute__((ext_vector_type(8))) unsigned short u16x8;
typedef __attribute__((ext_vector_type(4))) unsigned short u16x4;

__device__ __forceinline__ unsigned short f2bf(float f) {
    unsigned int u = __builtin_bit_cast(unsigned int, f);
    u = (u + 0x7FFFu + ((u >> 16) & 1u)) >> 16;
    return (unsigned short)u;
}

#define GLDS16(gptr, lptr)                                                         \
    __builtin_amdgcn_global_load_lds(                                              \
        (const __attribute__((address_space(1))) void*)(gptr),                     \
        (__attribute__((address_space(3))) void*)(lptr), 16, 0, 0)

#define BAR()  asm volatile("s_barrier" ::: "memory")
#define SBAR() __builtin_amdgcn_sched_barrier(0)
#define VM0()  asm volatile("s_waitcnt vmcnt(0)" ::: "memory")

// ---------------- Routing (+ fused x fp32->bf16 conversion + out zeroing) ----------
__global__ __launch_bounds__(256) void route_kernel(
    const float* __restrict__ x, const float* __restrict__ Wg,
    int* __restrict__ counts, int* __restrict__ lists, float* __restrict__ pw,
    unsigned short* __restrict__ xb, float* __restrict__ outz)
{
    // fold the d_out zeroing into this kernel (saves a 32MB memset dispatch):
    // 2048 blocks x 256 thr x 16 floats = 8192*1024 exactly.
    {
        size_t base = ((size_t)blockIdx.x * 256 + threadIdx.x) * 16;
        float4 z = {0.f, 0.f, 0.f, 0.f};
#pragma unroll
        for (int j = 0; j < 4; ++j)
            *reinterpret_cast<float4*>(outz + base + j * 4) = z;
    }

    int tok  = (int)((blockIdx.x * blockDim.x + threadIdx.x) >> 6);
    int lane = threadIdx.x & 63;
    if (tok >= T_TOK) return;

    const float* xr = x + (size_t)tok * DM;
    float acc[NE];
#pragma unroll
    for (int e = 0; e < NE; ++e) acc[e] = 0.f;

    for (int i = lane; i < DM; i += 64) {
        float xv = xr[i];
        const float* wr = Wg + (size_t)i * NE;
#pragma unroll
        for (int e = 0; e < NE; ++e) acc[e] += xv * wr[e];
    }

    // fused bf16 conversion of this token's row (re-reads from L1/L2, hot)
    if (xb) {
        unsigned short* xrow = xb + (size_t)tok * DM;
#pragma unroll
        for (int i = lane * 4; i < DM; i += 256) {
            float4 v = *reinterpret_cast<const float4*>(xr + i);
            u16x4 o;
            o[0] = f2bf(v.x); o[1] = f2bf(v.y); o[2] = f2bf(v.z); o[3] = f2bf(v.w);
            *reinterpret_cast<u16x4*>(xrow + i) = o;
        }
    }

#pragma unroll
    for (int e = 0; e < NE; ++e) {
#pragma unroll
        for (int off = 32; off > 0; off >>= 1)
            acc[e] += __shfl_xor(acc[e], off, 64);
    }

    if (lane == 0) {
        int i0 = 0; float v0 = acc[0];
#pragma unroll
        for (int e = 1; e < NE; ++e) if (acc[e] > v0) { v0 = acc[e]; i0 = e; }
        int i1 = -1; float v1 = -INFINITY;
#pragma unroll
        for (int e = 0; e < NE; ++e) if (e != i0 && acc[e] > v1) { v1 = acc[e]; i1 = e; }
        float e1 = __expf(v1 - v0);
        float s  = 1.f + e1;
        int p0 = tok * 2, p1 = tok * 2 + 1;
        pw[p0] = 1.f / s;
        pw[p1] = e1 / s;
        int pos0 = atomicAdd(&counts[i0], 1);
        lists[i0 * T_TOK + pos0] = p0;
        int pos1 = atomicAdd(&counts[i1], 1);
        lists[i1 * T_TOK + pos1] = p1;
    }
}

// offsets + 128-row tile table (e<<20 | slot0) + live tile count
__global__ void offsets_kernel(const int* __restrict__ counts, int* __restrict__ offsets,
                               unsigned* __restrict__ table, int* __restrict__ ntp)
{
    if (threadIdx.x == 0) {
        int s = 0, ti = 0;
        for (int e = 0; e < NE; ++e) {
            offsets[e] = s;
            int cnt = counts[e];
            for (int t0 = 0; t0 < cnt; t0 += 128)
                table[ti++] = ((unsigned)e << 20) | (unsigned)t0;
            s += cnt;
        }
        ntp[0] = ti;
        for (; ti < MAXT; ++ti) table[ti] = 0xFFFFFFFFu;
    }
}

// -------- merged W transpose: W1 and W2 in ONE launch (runtime K,N) --------
// [E][K][N] fp32 -> [E][N][K] bf16, 64x64 tiles, 16B/lane both sides.
__global__ __launch_bounds__(256) void transpose_conv_all(
    const float* __restrict__ W1, const float* __restrict__ W2,
    unsigned short* __restrict__ w1t, unsigned short* __restrict__ w2t)
{
    int id = blockIdx.x;
    const float* W; unsigned short* Wt; int K, N, e, k0, n0;
    if (id < 8192) {           // W1: K=1024,N=4096 -> 16x64 tiles = 1024/expert
        W = W1; Wt = w1t; K = DM; N = DF;
        e = id >> 10; int r = id & 1023;
        k0 = (r & 15) * 64; n0 = (r >> 4) * 64;
    } else {                   // W2: K=4096,N=1024 -> 64x16 tiles = 1024/expert
        id -= 8192;
        W = W2; Wt = w2t; K = DF; N = DM;
        e = id >> 10; int r = id & 1023;
        k0 = (r >> 4) * 64; n0 = (r & 15) * 64;
    }
    const float* We = W + (size_t)e * K * N;
    unsigned short* Wte = Wt + (size_t)e * K * N;

    __shared__ unsigned short t[64][73];
    int c4 = (threadIdx.x & 15) * 4;
    int rr0 = threadIdx.x >> 4;             // 0..15
#pragma unroll
    for (int i = 0; i < 4; ++i) {
        int rr = rr0 + i * 16;
        float4 v = *reinterpret_cast<const float4*>(We + (size_t)(k0 + rr) * N + n0 + c4);
        t[rr][c4 + 0] = f2bf(v.x); t[rr][c4 + 1] = f2bf(v.y);
        t[rr][c4 + 2] = f2bf(v.z); t[rr][c4 + 3] = f2bf(v.w);
    }
    __syncthreads();
    int kc = (threadIdx.x & 7) * 8;
    int rn = threadIdx.x >> 3;              // 0..31
#pragma unroll
    for (int i = 0; i < 2; ++i) {
        int nn = rn + i * 32;
        u16x8 o;
#pragma unroll
        for (int j = 0; j < 8; ++j) o[j] = t[kc + j][nn];
        *reinterpret_cast<u16x8*>(Wte + (size_t)(n0 + nn) * K + k0 + kc) = o;
    }
}

// ---------------- grouped GEMM: 128x128, BK=64, one barrier per K-tile -------------
// 4 waves (2M x 2N), per-wave 64x64, acc 4x4. LDS 64 KB = 2 dbuf x (A 16K + B 16K)
// -> 2 blocks/CU (8 waves/CU). Catalog minimal T3+T4 recipe (m248v2, +10% grouped):
//   loop: STAGE(next tile, issued FIRST) ; compute(cur) ; sched_barrier ;
//         vmcnt(0) ; s_barrier            <- ONE barrier per BK=64 (r4/r5: two per 32)
// Stage cover = a full compute phase (~2x16 MFMA + 16 ds_read_b128).
// Slab = 128 rows x 128B (8 granules x 16B). Swizzle: store-side source granule
// g = (t&7)^((t>>3)&7); read granule (ks*4+l4)^(l15&7) -> 2 lanes/bank both sides.
template<int N, int K, int SPLITK, bool IS_G1>
__global__ __launch_bounds__(256, 2) void moe_gemm13(
    const unsigned short* __restrict__ A,
    const unsigned short* __restrict__ Wt,
    const int* __restrict__ counts, const int* __restrict__ offsets,
    const int* __restrict__ lists, const unsigned* __restrict__ table,
    const int* __restrict__ ntp, const float* __restrict__ pw,
    unsigned short* __restrict__ Hout, float* __restrict__ Oout)
{
    constexpr int NT  = N / 128;
    constexpr int PAN = NT * SPLITK;
    constexpr int KS  = K / SPLITK;
    constexpr int NC  = KS / 64;
    static_assert(NC >= 2, "pipeline depth");

    __shared__ __attribute__((aligned(16))) char lds[65536];
    // A slab s: lds + s*16384 ; B slab s: lds + 32768 + s*16384

    int ntl  = ntp[0];
    int live = ntl * PAN;
    int orig = blockIdx.x;
    if (orig >= live) return;
    int q = live >> 3, r = live & 7;
    int xq = orig & 7, ib = orig >> 3;
    int work = (xq < r ? xq * (q + 1) : r * (q + 1) + (xq - r) * q) + ib;
    int rt    = work / PAN;                 // rt-major: neighbors share A-tile
    int panel = work - rt * PAN;
    int nt    = panel >> (SPLITK - 1);      // SPLITK is 1 or 2
    int sk    = panel & (SPLITK - 1);
    int koff  = sk * KS;

    unsigned te = table[rt];
    int e     = (int)(te >> 20);
    int slot0 = (int)(te & 0xFFFFFu);
    int cnt   = counts[e];
    int off   = offsets[e];
    int ntile = nt * 128;

    int tid  = threadIdx.x;
    int lane = tid & 63;
    int wid  = tid >> 6;
    int wm = wid >> 1;                  // 0..1
    int wn = wid & 1;                   // 0..1
    int l15 = lane & 15, l4 = lane >> 4;

    const unsigned short* Be = Wt + (size_t)e * N * K;

    // ---- staging: thread t -> row (u*32 + t>>3), slot t&7; source granule
    // pre-swizzled g = (t&7)^((t>>3)&7)  (row&7 == (t>>3)&7 since u*32 % 8 == 0)
    int g8 = ((tid & 7) ^ ((tid >> 3) & 7)) * 8;
    int r0 = tid >> 3;                  // 0..31
    unsigned aOff[4], bOff[4];
#pragma unroll
    for (int u = 0; u < 4; ++u) {
        int sl = slot0 + u * 32 + r0;
        unsigned grow;
        if (IS_G1) grow = (sl < cnt) ? (unsigned)(lists[e * T_TOK + sl] >> 1) : 0u;
        else       grow = (unsigned)(off + ((sl < cnt) ? sl : slot0));
        aOff[u] = grow * (unsigned)K + (unsigned)(koff + g8);
        bOff[u] = (unsigned)(ntile + u * 32 + r0) * (unsigned)K + (unsigned)(koff + g8);
    }

    auto stage = [&](int s, int c) {
        int ko = c * 64;
        char* dA = lds + s * 16384 + tid * 16;
        char* dB = lds + 32768 + s * 16384 + tid * 16;
#pragma unroll
        for (int u = 0; u < 4; ++u) GLDS16(A + aOff[u] + ko, dA + u * 4096);
#pragma unroll
        for (int u = 0; u < 4; ++u) GLDS16(Be + bOff[u] + ko, dB + u * 4096);
    };

    // ---- fragment read bases: row*128B + swizzled granule*16; ks flips bit6
    int swz = (l4 ^ (l15 & 7)) * 16;
    int aRd = wm * 8192 + l15 * 128 + swz;
    int bRd = wn * 8192 + l15 * 128 + swz;

    f32x4 acc[4][4];
#pragma unroll
    for (int m = 0; m < 4; ++m)
#pragma unroll
        for (int n = 0; n < 4; ++n) acc[m][n] = (f32x4){0.f, 0.f, 0.f, 0.f};

    auto compute = [&](int s) {
        const char* Ab = lds + s * 16384;
        const char* Bb = lds + 32768 + s * 16384;
#pragma unroll
        for (int ks = 0; ks < 2; ++ks) {
            const int x = ks * 64;
            s16x8 af[4], bf[4];
#pragma unroll
            for (int m = 0; m < 4; ++m)
                af[m] = *reinterpret_cast<const s16x8*>(Ab + ((aRd + m * 2048) ^ x));
#pragma unroll
            for (int n = 0; n < 4; ++n)
                bf[n] = *reinterpret_cast<const s16x8*>(Bb + ((bRd + n * 2048) ^ x));
            __builtin_amdgcn_s_setprio(1);
#pragma unroll
            for (int n = 0; n < 4; ++n)
#pragma unroll
                for (int m = 0; m < 4; ++m)
                    acc[m][n] = __builtin_amdgcn_mfma_f32_16x16x32_bf16(
                        af[m], bf[n], acc[m][n], 0, 0, 0);
            __builtin_amdgcn_s_setprio(0);
        }
    };

    // ---- pipeline: stage-first, one vmcnt(0)+barrier per K-tile ----
    stage(0, 0);
    VM0(); BAR();
    int cur = 0;
    for (int c = 0; c < NC; ++c) {
        if (c + 1 < NC) stage(cur ^ 1, c + 1);   // issue next tile BEFORE compute
        compute(cur);
        SBAR();                                   // pin MFMAs+lgkm before the sync
        VM0(); BAR();                             // next tile resident; reads retired
        cur ^= 1;
    }

    // ---- epilogue: C/D col = lane&15, row = (lane>>4)*4 + rr ----
#pragma unroll
    for (int m = 0; m < 4; ++m) {
        int trow = wm * 64 + m * 16 + l4 * 4;
#pragma unroll
        for (int rr = 0; rr < 4; ++rr) {
            int slot = slot0 + trow + rr;
            if (slot >= cnt) continue;
            if (IS_G1) {
                unsigned short* hr = Hout + (size_t)(off + slot) * N;
#pragma unroll
                for (int n = 0; n < 4; ++n) {
                    int col = ntile + wn * 64 + n * 16 + l15;
                    float v = acc[m][n][rr];
                    float s = v / (1.f + __expf(-v));
                    hr[col] = f2bf(s);
                }
            } else {
                int p = lists[e * T_TOK + slot];
                float w = pw[p];
                float* orow = Oout + (size_t)(p >> 1) * DM;
#pragma unroll
                for (int n = 0; n < 4; ++n) {
                    int col = ntile + wn * 64 + n * 16 + l15;
                    atomicAdd(orow + col, w * acc[m][n][rr]);
                }
            }
        }
    }
}

// ================= fallback (round-1 validated fp32 path) =================
#define BMF 16
#define BFF 256
__global__ __launch_bounds__(256) void expert_gemm_f32(
    const float* __restrict__ x, const float* __restrict__ W1, const float* __restrict__ W2,
    const int* __restrict__ counts, const int* __restrict__ lists, const float* __restrict__ pw,
    float* __restrict__ out)
{
    int e    = blockIdx.y;
    int tile = blockIdx.x;
    int cnt  = counts[e];
    int start = tile * BMF;
    if (start >= cnt) return;

    __shared__ float xs[BMF][DM];
    __shared__ float hs[BMF][BFF];
    __shared__ int   toks[BMF];
    __shared__ float wgt[BMF];

    int tid = threadIdx.x;
    int nm  = cnt - start; if (nm > BMF) nm = BMF;

    if (tid < BMF) {
        if (tid < nm) {
            int p = lists[e * T_TOK + start + tid];
            toks[tid] = p >> 1;
            wgt[tid]  = pw[p];
        } else { toks[tid] = -1; wgt[tid] = 0.f; }
    }
    __syncthreads();
    for (int m = 0; m < BMF; ++m) {
        int t = toks[m];
        const float* xr = (t >= 0) ? (x + (size_t)t * DM) : nullptr;
        for (int i = tid; i < DM; i += 256) xs[m][i] = (t >= 0) ? xr[i] : 0.f;
    }
    __syncthreads();

    const float* W1e = W1 + (size_t)e * DM * DF;
    const float* W2e = W2 + (size_t)e * DF * DM;
    float acc[BMF][4];
#pragma unroll
    for (int m = 0; m < BMF; ++m)
#pragma unroll
        for (int c = 0; c < 4; ++c) acc[m][c] = 0.f;

    for (int fc = 0; fc < DF; fc += BFF) {
        float hacc[BMF];
#pragma unroll
        for (int m = 0; m < BMF; ++m) hacc[m] = 0.f;
        const float* w1col = W1e + fc + tid;
#pragma unroll 4
        for (int i = 0; i < DM; ++i) {
            float w1v = w1col[(size_t)i * DF];
#pragma unroll
            for (int m = 0; m < BMF; ++m) hacc[m] += xs[m][i] * w1v;
        }
        __syncthreads();
#pragma unroll
        for (int m = 0; m < BMF; ++m) {
            float v = hacc[m];
            hs[m][tid] = v / (1.f + __expf(-v));
        }
        __syncthreads();
        const float* w2base = W2e + (size_t)fc * DM + tid * 4;
        for (int f = 0; f < BFF; ++f) {
            float4 w2v = *reinterpret_cast<const float4*>(w2base + (size_t)f * DM);
#pragma unroll
            for (int m = 0; m < BMF; ++m) {
                float h = hs[m][f];
                acc[m][0] += h * w2v.x; acc[m][1] += h * w2v.y;
                acc[m][2] += h * w2v.z; acc[m][3] += h * w2v.w;
            }
        }
        __syncthreads();
    }
    int c0 = tid * 4;
#pragma unroll
    for (int m = 0; m < BMF; ++m) {
        int t = toks[m];
        if (t < 0) continue;
        float w = wgt[m];
        float* op = out + (size_t)t * DM + c0;
        atomicAdd(op + 0, w * acc[m][0]);
        atomicAdd(op + 1, w * acc[m][1]);
        atomicAdd(op + 2, w * acc[m][2]);
        atomicAdd(op + 3, w * acc[m][3]);
    }
}

// ================= launch =================
extern "C" void kernel_launch(void* const* d_in, const int* in_sizes, int n_in,
                              void* d_out, int out_size, void* d_ws, size_t ws_size,
                              hipStream_t stream)
{
    const float* x  = (const float*)d_in[0];
    const float* Wg = (const float*)d_in[1];
    const float* W1 = (const float*)d_in[2];
    const float* W2 = (const float*)d_in[3];
    float* out = (float*)d_out;

    char* ws = (char*)d_ws;
    int*      counts  = (int*)(ws + 0);
    int*      offsets = (int*)(ws + 64);
    int*      ntp     = (int*)(ws + 128);
    unsigned* table   = (unsigned*)(ws + 256);        // 144*4 = 576 B
    int*      lists   = (int*)(ws + 2048);            // 256 KB
    float*    pw      = (float*)(ws + 2048 + 262144); // 64 KB

    const size_t o_xb  = 524288;
    const size_t sz_xb = (size_t)T_TOK * DM * 2;              // 16 MB
    const size_t o_w1t = o_xb + sz_xb;
    const size_t sz_w  = (size_t)NE * DM * DF * 2;            // 64 MB each
    const size_t o_w2t = o_w1t + sz_w;
    const size_t o_h   = o_w2t + sz_w;
    const size_t sz_h  = (size_t)(2 * T_TOK) * DF * 2;        // 134 MB
    const size_t NEEDED = o_h + sz_h;

    bool fast = (ws_size >= NEEDED);
    unsigned short* xb = fast ? (unsigned short*)(ws + o_xb) : nullptr;

    hipMemsetAsync(counts, 0, 64, stream);
    route_kernel<<<T_TOK / 4, 256, 0, stream>>>(x, Wg, counts, lists, pw, xb, out);

    if (fast) {
        unsigned short* w1t = (unsigned short*)(ws + o_w1t);
        unsigned short* w2t = (unsigned short*)(ws + o_w2t);
        unsigned short* H   = (unsigned short*)(ws + o_h);

        offsets_kernel<<<1, 64, 0, stream>>>(counts, offsets, table, ntp);
        transpose_conv_all<<<16384, 256, 0, stream>>>(W1, W2, w1t, w2t);
        // G1: [cnt x 1024] @ W1t -> silu -> H (bf16), 128x128 tiles
        moe_gemm13<DF, DM, 1, true><<<dim3(MAXT * 32), 256, 0, stream>>>(
            xb, w1t, counts, offsets, lists, table, ntp, pw, H, nullptr);
        // G2: H @ W2t -> gated atomic-add into out, 128x128 tiles, split-K 2
        moe_gemm13<DM, DF, 2, false><<<dim3(MAXT * 16), 256, 0, stream>>>(
            H, w2t, counts, offsets, lists, table, ntp, pw, nullptr, out);
    } else {
        dim3 grid(T_TOK / BMF, NE);
        expert_gemm_f32<<<grid, 256, 0, stream>>>(x, W1, W2, counts, lists, pw, out);
    }
}

// Round 7
// 675.752 us; speedup vs baseline: 1.1166x; 1.1166x over previous
//
#include <hip/hip_runtime.h>
#include <hip/hip_bf16.h>
#include <math.h>

#define T_TOK 8192
#define DM 1024
#define DF 4096
#define NE 8
#define MAXT 72    // max 256-row tiles: 64 full + 7 partials + slack

typedef __attribute__((ext_vector_type(4))) float  f32x4;
typedef __attribute__((ext_vector_type(8))) short  s16x8;
typedef __attribute__((ext_vector_type(8))) unsigned short u16x8;
typedef __attribute__((ext_vector_type(4))) unsigned short u16x4;

__device__ __forceinline__ unsigned short f2bf(float f) {
    unsigned int u = __builtin_bit_cast(unsigned int, f);
    u = (u + 0x7FFFu + ((u >> 16) & 1u)) >> 16;
    return (unsigned short)u;
}

#define GLDS16(gptr, lptr)                                                         \
    __builtin_amdgcn_global_load_lds(                                              \
        (const __attribute__((address_space(1))) void*)(gptr),                     \
        (__attribute__((address_space(3))) void*)(lptr), 16, 0, 0)

#define BAR() asm volatile("s_barrier" ::: "memory")

template<int W>
__device__ __forceinline__ void waitvm() {
    if constexpr (W == 6)      asm volatile("s_waitcnt vmcnt(6)" ::: "memory");
    else if constexpr (W == 3) asm volatile("s_waitcnt vmcnt(3)" ::: "memory");
    else                       asm volatile("s_waitcnt vmcnt(0)" ::: "memory");
}

// ------- Routing: single pass gating + bf16 conversion + d_out zeroing -------
// One wave per token. Vectorized: per lane 4 steps x {float4 x, 8 float4 Wg rows}.
__global__ __launch_bounds__(256) void route_kernel(
    const float* __restrict__ x, const float* __restrict__ Wg,
    int* __restrict__ counts, int* __restrict__ lists, float* __restrict__ pw,
    unsigned short* __restrict__ xb, float* __restrict__ outz)
{
    // fold d_out zeroing here (saves a 32MB memset dispatch):
    // 2048 blocks x 256 thr x 16 floats = 8192*1024 exactly.
    {
        size_t base = ((size_t)blockIdx.x * 256 + threadIdx.x) * 16;
        float4 z = {0.f, 0.f, 0.f, 0.f};
#pragma unroll
        for (int j = 0; j < 4; ++j)
            *reinterpret_cast<float4*>(outz + base + j * 4) = z;
    }

    int tok  = (int)((blockIdx.x * blockDim.x + threadIdx.x) >> 6);
    int lane = threadIdx.x & 63;
    if (tok >= T_TOK) return;

    const float* xr = x + (size_t)tok * DM;
    unsigned short* xrow = xb ? (xb + (size_t)tok * DM) : nullptr;

    float acc[NE];
#pragma unroll
    for (int e = 0; e < NE; ++e) acc[e] = 0.f;

#pragma unroll
    for (int s = 0; s < 4; ++s) {
        int i = s * 256 + lane * 4;
        float4 xv = *reinterpret_cast<const float4*>(xr + i);
#pragma unroll
        for (int j = 0; j < 4; ++j) {
            const float* wr = Wg + (size_t)(i + j) * NE;
            float4 w0 = *reinterpret_cast<const float4*>(wr);
            float4 w1 = *reinterpret_cast<const float4*>(wr + 4);
            float xs = (j == 0) ? xv.x : (j == 1) ? xv.y : (j == 2) ? xv.z : xv.w;
            acc[0] += xs * w0.x; acc[1] += xs * w0.y;
            acc[2] += xs * w0.z; acc[3] += xs * w0.w;
            acc[4] += xs * w1.x; acc[5] += xs * w1.y;
            acc[6] += xs * w1.z; acc[7] += xs * w1.w;
        }
        if (xrow) {
            u16x4 o;
            o[0] = f2bf(xv.x); o[1] = f2bf(xv.y); o[2] = f2bf(xv.z); o[3] = f2bf(xv.w);
            *reinterpret_cast<u16x4*>(xrow + i) = o;
        }
    }

#pragma unroll
    for (int e = 0; e < NE; ++e) {
#pragma unroll
        for (int off = 32; off > 0; off >>= 1)
            acc[e] += __shfl_xor(acc[e], off, 64);
    }

    if (lane == 0) {
        int i0 = 0; float v0 = acc[0];
#pragma unroll
        for (int e = 1; e < NE; ++e) if (acc[e] > v0) { v0 = acc[e]; i0 = e; }
        int i1 = -1; float v1 = -INFINITY;
#pragma unroll
        for (int e = 0; e < NE; ++e) if (e != i0 && acc[e] > v1) { v1 = acc[e]; i1 = e; }
        float e1 = __expf(v1 - v0);
        float s  = 1.f + e1;
        int p0 = tok * 2, p1 = tok * 2 + 1;
        pw[p0] = 1.f / s;
        pw[p1] = e1 / s;
        int pos0 = atomicAdd(&counts[i0], 1);
        lists[i0 * T_TOK + pos0] = p0;
        int pos1 = atomicAdd(&counts[i1], 1);
        lists[i1 * T_TOK + pos1] = p1;
    }
}

// -------- merged W transpose: W1 and W2 in ONE launch (runtime K,N) --------
// [E][K][N] fp32 -> [E][N][K] bf16, 64x64 tiles, 16B/lane both sides.
__global__ __launch_bounds__(256) void transpose_conv_all(
    const float* __restrict__ W1, const float* __restrict__ W2,
    unsigned short* __restrict__ w1t, unsigned short* __restrict__ w2t)
{
    int id = blockIdx.x;
    const float* W; unsigned short* Wt; int K, N, e, k0, n0;
    if (id < 8192) {           // W1: K=1024,N=4096 -> 16x64 tiles = 1024/expert
        W = W1; Wt = w1t; K = DM; N = DF;
        e = id >> 10; int r = id & 1023;
        k0 = (r & 15) * 64; n0 = (r >> 4) * 64;
    } else {                   // W2: K=4096,N=1024 -> 64x16 tiles = 1024/expert
        id -= 8192;
        W = W2; Wt = w2t; K = DF; N = DM;
        e = id >> 10; int r = id & 1023;
        k0 = (r >> 4) * 64; n0 = (r & 15) * 64;
    }
    const float* We = W + (size_t)e * K * N;
    unsigned short* Wte = Wt + (size_t)e * K * N;

    __shared__ unsigned short t[64][73];
    int c4 = (threadIdx.x & 15) * 4;
    int rr0 = threadIdx.x >> 4;             // 0..15
#pragma unroll
    for (int i = 0; i < 4; ++i) {
        int rr = rr0 + i * 16;
        float4 v = *reinterpret_cast<const float4*>(We + (size_t)(k0 + rr) * N + n0 + c4);
        t[rr][c4 + 0] = f2bf(v.x); t[rr][c4 + 1] = f2bf(v.y);
        t[rr][c4 + 2] = f2bf(v.z); t[rr][c4 + 3] = f2bf(v.w);
    }
    __syncthreads();
    int kc = (threadIdx.x & 7) * 8;
    int rn = threadIdx.x >> 3;              // 0..31
#pragma unroll
    for (int i = 0; i < 2; ++i) {
        int nn = rn + i * 32;
        u16x8 o;
#pragma unroll
        for (int j = 0; j < 8; ++j) o[j] = t[kc + j][nn];
        *reinterpret_cast<u16x8*>(Wte + (size_t)(n0 + nn) * K + k0 + kc) = o;
    }
}

// ---------------- occupancy-first grouped GEMM (r4 core, self-derived table) --------
// BM=256, BN=128, BK=32, 512 thr, 8 waves (4M x 2N), per-wave 64x64.
// 2 blocks/CU = 16 waves/CU. Ring-3 slabs, depth-3 prefetch, counted vmcnt(6).
// LDS 72 KB: A 3x16K + B 3x8K; 2 blocks/CU = 144 KB <= 160 KB.
// Swizzle (measured 0 conflicts r0/r4): store granule (tid&3)^((tid>>3)&3),
// read slot l4^((l15>>1)&3).
// NEW vs r4: no offsets/table kernel -- each block derives (e, slot0, off, live)
// from counts[8] with an unrolled found-flag scan (all indices compile-time).
template<int N, int K, int SPLITK, bool IS_G1>
__global__ __launch_bounds__(512, 4) void moe_gemm14(
    const unsigned short* __restrict__ A,
    const unsigned short* __restrict__ Wt,
    const int* __restrict__ counts, const int* __restrict__ lists,
    const float* __restrict__ pw,
    unsigned short* __restrict__ Hout, float* __restrict__ Oout)
{
    constexpr int NT  = N / 128;
    constexpr int PAN = NT * SPLITK;
    constexpr int KS  = K / SPLITK;
    constexpr int NC  = KS / 32;
    static_assert(NC >= 4, "pipeline depth");

    __shared__ __attribute__((aligned(16))) char lds[73728];
    // A slot s: lds + s*16384 (256 rows x 64B); B slot s: lds + 49152 + s*8192

    int cnts[NE];
#pragma unroll
    for (int i = 0; i < NE; ++i) cnts[i] = counts[i];
    int ntl = 0;
#pragma unroll
    for (int i = 0; i < NE; ++i) ntl += (cnts[i] + 255) >> 8;

    int live = ntl * PAN;
    int orig = blockIdx.x;
    if (orig >= live) return;
    int q = live >> 3, r = live & 7;
    int xq = orig & 7, ib = orig >> 3;
    int work = (xq < r ? xq * (q + 1) : r * (q + 1) + (xq - r) * q) + ib;
    int rt    = work / PAN;                 // rt-major: neighbors share A-tile
    int panel = work - rt * PAN;
    int nt    = panel >> (SPLITK - 1);      // SPLITK is 1 or 2
    int sk    = panel & (SPLITK - 1);
    int koff  = sk * KS;

    // derive (e, slot0, off, cnt) from counts -- replaces offsets_kernel/table
    int e = 0, tb = 0, off = 0, cnt = 0;
    {
        int ctb = 0, cob = 0; bool found = false;
#pragma unroll
        for (int i = 0; i < NE; ++i) {
            int ti = (cnts[i] + 255) >> 8;
            if (!found && rt < ctb + ti) { e = i; tb = ctb; off = cob; cnt = cnts[i]; found = true; }
            ctb += ti; cob += cnts[i];
        }
    }
    int slot0 = (rt - tb) << 8;
    int ntile = nt * 128;

    int tid  = threadIdx.x;
    int lane = tid & 63;
    int wid  = tid >> 6;
    int wm = wid >> 1;                  // 0..3
    int wn = wid & 1;                   // 0..1
    int l15 = lane & 15, l4 = lane >> 4;

    const unsigned short* Be = Wt + (size_t)e * N * K;

    // ---- staging offsets (elements). swizzle: granule ^= (row>>1)&3 ----
    int ssw = ((tid & 3) ^ ((tid >> 3) & 3)) * 8;
    unsigned aOff0, aOff1, bOff;
    {
        int r0 = tid >> 2;                  // 0..127
#pragma unroll
        for (int u = 0; u < 2; ++u) {
            int sl = slot0 + u * 128 + r0;
            unsigned grow;
            if (IS_G1) grow = (sl < cnt) ? (unsigned)(lists[e * T_TOK + sl] >> 1) : 0u;
            else       grow = (unsigned)(off + ((sl < cnt) ? sl : slot0));
            unsigned v = grow * (unsigned)K + (unsigned)(koff + ssw);
            if (u == 0) aOff0 = v; else aOff1 = v;
        }
        bOff = (unsigned)(ntile + r0) * (unsigned)K + (unsigned)(koff + ssw);
    }

    auto stage = [&](int s, int c) {
        int ko = c * 32;
        char* dA = lds + s * 16384 + tid * 16;
        char* dB = lds + 49152 + s * 8192 + tid * 16;
        GLDS16(A + aOff0 + ko, dA);
        GLDS16(A + aOff1 + ko, dA + 8192);
        GLDS16(Be + bOff + ko, dB);
    };

    // ---- fragment read bases (swizzled; row stride 64B) ----
    int swzb = (l4 ^ ((l15 >> 1) & 3)) * 16;
    int aRd = (wm * 64 + l15) * 64 + swzb;
    int bRd = (wn * 64 + l15) * 64 + swzb;

    f32x4 acc[4][4];
#pragma unroll
    for (int m = 0; m < 4; ++m)
#pragma unroll
        for (int n = 0; n < 4; ++n) acc[m][n] = (f32x4){0.f, 0.f, 0.f, 0.f};

    auto compute = [&](int s) {
        const char* Ab = lds + s * 16384;
        const char* Bb = lds + 49152 + s * 8192;
        s16x8 af[4];
#pragma unroll
        for (int m = 0; m < 4; ++m)
            af[m] = *reinterpret_cast<const s16x8*>(Ab + aRd + m * 1024);
        __builtin_amdgcn_s_setprio(1);
#pragma unroll
        for (int n = 0; n < 4; ++n) {
            s16x8 bf = *reinterpret_cast<const s16x8*>(Bb + bRd + n * 1024);
#pragma unroll
            for (int m = 0; m < 4; ++m)
                acc[m][n] = __builtin_amdgcn_mfma_f32_16x16x32_bf16(af[m], bf, acc[m][n], 0, 0, 0);
        }
        __builtin_amdgcn_s_setprio(0);
    };

    // ---- pipeline: 3-slot ring, depth-3 prefetch, counted vmcnt(6) ----
    stage(0, 0); stage(1, 1); stage(2, 2);
    int sslot = 0;
    for (int c = 0; c < NC; ++c) {
        if (c + 2 < NC)      waitvm<6>();   // chunk c done; c+1,c+2 in flight
        else if (c + 1 < NC) waitvm<3>();
        else                 waitvm<0>();
        BAR();
        compute(sslot);
        BAR();
        if (c + 3 < NC) stage(sslot, c + 3);
        sslot = (sslot == 2) ? 0 : sslot + 1;
    }

    // ---- epilogue: C/D col = lane&15, row = (lane>>4)*4 + rr ----
#pragma unroll
    for (int m = 0; m < 4; ++m) {
        int trow = wm * 64 + m * 16 + l4 * 4;
#pragma unroll
        for (int rr = 0; rr < 4; ++rr) {
            int slot = slot0 + trow + rr;
            if (slot >= cnt) continue;
            if (IS_G1) {
                unsigned short* hr = Hout + (size_t)(off + slot) * N;
#pragma unroll
                for (int n = 0; n < 4; ++n) {
                    int col = ntile + wn * 64 + n * 16 + l15;
                    float v = acc[m][n][rr];
                    float s = v / (1.f + __expf(-v));
                    hr[col] = f2bf(s);
                }
            } else {
                int p = lists[e * T_TOK + slot];
                float w = pw[p];
                float* orow = Oout + (size_t)(p >> 1) * DM;
#pragma unroll
                for (int n = 0; n < 4; ++n) {
                    int col = ntile + wn * 64 + n * 16 + l15;
                    atomicAdd(orow + col, w * acc[m][n][rr]);
                }
            }
        }
    }
}

// ================= fallback (round-1 validated fp32 path) =================
#define BMF 16
#define BFF 256
__global__ __launch_bounds__(256) void expert_gemm_f32(
    const float* __restrict__ x, const float* __restrict__ W1, const float* __restrict__ W2,
    const int* __restrict__ counts, const int* __restrict__ lists, const float* __restrict__ pw,
    float* __restrict__ out)
{
    int e    = blockIdx.y;
    int tile = blockIdx.x;
    int cnt  = counts[e];
    int start = tile * BMF;
    if (start >= cnt) return;

    __shared__ float xs[BMF][DM];
    __shared__ float hs[BMF][BFF];
    __shared__ int   toks[BMF];
    __shared__ float wgt[BMF];

    int tid = threadIdx.x;
    int nm  = cnt - start; if (nm > BMF) nm = BMF;

    if (tid < BMF) {
        if (tid < nm) {
            int p = lists[e * T_TOK + start + tid];
            toks[tid] = p >> 1;
            wgt[tid]  = pw[p];
        } else { toks[tid] = -1; wgt[tid] = 0.f; }
    }
    __syncthreads();
    for (int m = 0; m < BMF; ++m) {
        int t = toks[m];
        const float* xr = (t >= 0) ? (x + (size_t)t * DM) : nullptr;
        for (int i = tid; i < DM; i += 256) xs[m][i] = (t >= 0) ? xr[i] : 0.f;
    }
    __syncthreads();

    const float* W1e = W1 + (size_t)e * DM * DF;
    const float* W2e = W2 + (size_t)e * DF * DM;
    float acc[BMF][4];
#pragma unroll
    for (int m = 0; m < BMF; ++m)
#pragma unroll
        for (int c = 0; c < 4; ++c) acc[m][c] = 0.f;

    for (int fc = 0; fc < DF; fc += BFF) {
        float hacc[BMF];
#pragma unroll
        for (int m = 0; m < BMF; ++m) hacc[m] = 0.f;
        const float* w1col = W1e + fc + tid;
#pragma unroll 4
        for (int i = 0; i < DM; ++i) {
            float w1v = w1col[(size_t)i * DF];
#pragma unroll
            for (int m = 0; m < BMF; ++m) hacc[m] += xs[m][i] * w1v;
        }
        __syncthreads();
#pragma unroll
        for (int m = 0; m < BMF; ++m) {
            float v = hacc[m];
            hs[m][tid] = v / (1.f + __expf(-v));
        }
        __syncthreads();
        const float* w2base = W2e + (size_t)fc * DM + tid * 4;
        for (int f = 0; f < BFF; ++f) {
            float4 w2v = *reinterpret_cast<const float4*>(w2base + (size_t)f * DM);
#pragma unroll
            for (int m = 0; m < BMF; ++m) {
                float h = hs[m][f];
                acc[m][0] += h * w2v.x; acc[m][1] += h * w2v.y;
                acc[m][2] += h * w2v.z; acc[m][3] += h * w2v.w;
            }
        }
        __syncthreads();
    }
    int c0 = tid * 4;
#pragma unroll
    for (int m = 0; m < BMF; ++m) {
        int t = toks[m];
        if (t < 0) continue;
        float w = wgt[m];
        float* op = out + (size_t)t * DM + c0;
        atomicAdd(op + 0, w * acc[m][0]);
        atomicAdd(op + 1, w * acc[m][1]);
        atomicAdd(op + 2, w * acc[m][2]);
        atomicAdd(op + 3, w * acc[m][3]);
    }
}

// ================= launch =================
extern "C" void kernel_launch(void* const* d_in, const int* in_sizes, int n_in,
                              void* d_out, int out_size, void* d_ws, size_t ws_size,
                              hipStream_t stream)
{
    const float* x  = (const float*)d_in[0];
    const float* Wg = (const float*)d_in[1];
    const float* W1 = (const float*)d_in[2];
    const float* W2 = (const float*)d_in[3];
    float* out = (float*)d_out;

    char* ws = (char*)d_ws;
    int*      counts  = (int*)(ws + 0);
    int*      lists   = (int*)(ws + 2048);            // 256 KB
    float*    pw      = (float*)(ws + 2048 + 262144); // 64 KB

    const size_t o_xb  = 524288;
    const size_t sz_xb = (size_t)T_TOK * DM * 2;              // 16 MB
    const size_t o_w1t = o_xb + sz_xb;
    const size_t sz_w  = (size_t)NE * DM * DF * 2;            // 64 MB each
    const size_t o_w2t = o_w1t + sz_w;
    const size_t o_h   = o_w2t + sz_w;
    const size_t sz_h  = (size_t)(2 * T_TOK) * DF * 2;        // 134 MB
    const size_t NEEDED = o_h + sz_h;

    bool fast = (ws_size >= NEEDED);
    unsigned short* xb = fast ? (unsigned short*)(ws + o_xb) : nullptr;

    hipMemsetAsync(counts, 0, 64, stream);
    route_kernel<<<T_TOK / 4, 256, 0, stream>>>(x, Wg, counts, lists, pw, xb, out);

    if (fast) {
        unsigned short* w1t = (unsigned short*)(ws + o_w1t);
        unsigned short* w2t = (unsigned short*)(ws + o_w2t);
        unsigned short* H   = (unsigned short*)(ws + o_h);

        transpose_conv_all<<<16384, 256, 0, stream>>>(W1, W2, w1t, w2t);
        // G1: [cnt x 1024] @ W1t -> silu -> H (bf16), 256x128 tiles
        moe_gemm14<DF, DM, 1, true><<<dim3(MAXT * 32), 512, 0, stream>>>(
            xb, w1t, counts, lists, pw, H, nullptr);
        // G2: H @ W2t -> gated atomic-add into out, 256x128 tiles, split-K 2
        moe_gemm14<DM, DF, 2, false><<<dim3(MAXT * 16), 512, 0, stream>>>(
            H, w2t, counts, lists, pw, nullptr, out);
    } else {
        dim3 grid(T_TOK / BMF, NE);
        expert_gemm_f32<<<grid, 256, 0, stream>>>(x, W1, W2, counts, lists, pw, out);
    }
}

// Round 8
// 670.639 us; speedup vs baseline: 1.1251x; 1.0076x over previous
//
#include <hip/hip_runtime.h>
#include <hip/hip_bf16.h>
#include <math.h>

#define T_TOK 8192
#define DM 1024
#define DF 4096
#define NE 8
#define MAXT 72    // max 256-row tiles: 64 full + 7 partials + slack

typedef __attribute__((ext_vector_type(4))) float  f32x4;
typedef __attribute__((ext_vector_type(8))) short  s16x8;
typedef __attribute__((ext_vector_type(8))) unsigned short u16x8;
typedef __attribute__((ext_vector_type(4))) unsigned short u16x4;

__device__ __forceinline__ unsigned short f2bf(float f) {
    unsigned int u = __builtin_bit_cast(unsigned int, f);
    u = (u + 0x7FFFu + ((u >> 16) & 1u)) >> 16;
    return (unsigned short)u;
}

#define GLDS16(gptr, lptr)                                                         \
    __builtin_amdgcn_global_load_lds(                                              \
        (const __attribute__((address_space(1))) void*)(gptr),                     \
        (__attribute__((address_space(3))) void*)(lptr), 16, 0, 0)

#define BAR() asm volatile("s_barrier" ::: "memory")

template<int W>
__device__ __forceinline__ void waitvm() {
    if constexpr (W == 6)      asm volatile("s_waitcnt vmcnt(6)" ::: "memory");
    else if constexpr (W == 3) asm volatile("s_waitcnt vmcnt(3)" ::: "memory");
    else                       asm volatile("s_waitcnt vmcnt(0)" ::: "memory");
}

// ======= prep kernel: route(+zero out, +x->bf16) and BOTH W transposes, ONE launch ==
// blocks 0..2047: route role (one wave per token, 4 tokens/block)
// blocks 2048..10239: W1 transpose  [E][1024][4096] fp32 -> [E][4096][1024] bf16
// blocks 10240..18431: W2 transpose [E][4096][1024] fp32 -> [E][1024][4096] bf16
// Route is VALU/gather-heavy, transposes are pure BW -> complementary in one launch.
__global__ __launch_bounds__(256) void prep_kernel(
    const float* __restrict__ x, const float* __restrict__ Wg,
    const float* __restrict__ W1, const float* __restrict__ W2,
    int* __restrict__ counts, int* __restrict__ lists, float* __restrict__ pw,
    unsigned short* __restrict__ xb, unsigned short* __restrict__ w1t,
    unsigned short* __restrict__ w2t, float* __restrict__ outz)
{
    __shared__ unsigned short t[64][73];
    int id = blockIdx.x;

    if (id < 2048) {
        // ---------------- route role ----------------
        // fold d_out zeroing: 2048 blocks x 256 thr x 16 floats = 8192*1024 exactly.
        {
            size_t base = ((size_t)id * 256 + threadIdx.x) * 16;
            float4 z = {0.f, 0.f, 0.f, 0.f};
#pragma unroll
            for (int j = 0; j < 4; ++j)
                *reinterpret_cast<float4*>(outz + base + j * 4) = z;
        }

        int tok  = (int)((id * 256 + threadIdx.x) >> 6);
        int lane = threadIdx.x & 63;

        const float* xr = x + (size_t)tok * DM;
        unsigned short* xrow = xb ? (xb + (size_t)tok * DM) : nullptr;

        float acc[NE];
#pragma unroll
        for (int e = 0; e < NE; ++e) acc[e] = 0.f;

#pragma unroll
        for (int s = 0; s < 4; ++s) {
            int i = s * 256 + lane * 4;
            float4 xv = *reinterpret_cast<const float4*>(xr + i);
#pragma unroll
            for (int j = 0; j < 4; ++j) {
                const float* wr = Wg + (size_t)(i + j) * NE;
                float4 w0 = *reinterpret_cast<const float4*>(wr);
                float4 w1 = *reinterpret_cast<const float4*>(wr + 4);
                float xs = (j == 0) ? xv.x : (j == 1) ? xv.y : (j == 2) ? xv.z : xv.w;
                acc[0] += xs * w0.x; acc[1] += xs * w0.y;
                acc[2] += xs * w0.z; acc[3] += xs * w0.w;
                acc[4] += xs * w1.x; acc[5] += xs * w1.y;
                acc[6] += xs * w1.z; acc[7] += xs * w1.w;
            }
            if (xrow) {
                u16x4 o;
                o[0] = f2bf(xv.x); o[1] = f2bf(xv.y); o[2] = f2bf(xv.z); o[3] = f2bf(xv.w);
                *reinterpret_cast<u16x4*>(xrow + i) = o;
            }
        }

#pragma unroll
        for (int e = 0; e < NE; ++e) {
#pragma unroll
            for (int off = 32; off > 0; off >>= 1)
                acc[e] += __shfl_xor(acc[e], off, 64);
        }

        if (lane == 0) {
            int i0 = 0; float v0 = acc[0];
#pragma unroll
            for (int e = 1; e < NE; ++e) if (acc[e] > v0) { v0 = acc[e]; i0 = e; }
            int i1 = -1; float v1 = -INFINITY;
#pragma unroll
            for (int e = 0; e < NE; ++e) if (e != i0 && acc[e] > v1) { v1 = acc[e]; i1 = e; }
            float e1 = __expf(v1 - v0);
            float s  = 1.f + e1;
            int p0 = tok * 2, p1 = tok * 2 + 1;
            pw[p0] = 1.f / s;
            pw[p1] = e1 / s;
            int pos0 = atomicAdd(&counts[i0], 1);
            lists[i0 * T_TOK + pos0] = p0;
            int pos1 = atomicAdd(&counts[i1], 1);
            lists[i1 * T_TOK + pos1] = p1;
        }
        return;
    }

    // ---------------- transpose roles ----------------
    if (!w1t) return;                       // fallback path: no transpose work
    int wid = id - 2048;
    const float* W; unsigned short* Wt; int K, N, e, k0, n0;
    if (wid < 8192) {          // W1: K=1024,N=4096 -> 16x64 tiles = 1024/expert
        W = W1; Wt = w1t; K = DM; N = DF;
        e = wid >> 10; int r = wid & 1023;
        k0 = (r & 15) * 64; n0 = (r >> 4) * 64;
    } else {                   // W2: K=4096,N=1024 -> 64x16 tiles = 1024/expert
        wid -= 8192;
        W = W2; Wt = w2t; K = DF; N = DM;
        e = wid >> 10; int r = wid & 1023;
        k0 = (r >> 4) * 64; n0 = (r & 15) * 64;
    }
    const float* We = W + (size_t)e * K * N;
    unsigned short* Wte = Wt + (size_t)e * K * N;

    int c4 = (threadIdx.x & 15) * 4;
    int rr0 = threadIdx.x >> 4;             // 0..15
#pragma unroll
    for (int i = 0; i < 4; ++i) {
        int rr = rr0 + i * 16;
        float4 v = *reinterpret_cast<const float4*>(We + (size_t)(k0 + rr) * N + n0 + c4);
        t[rr][c4 + 0] = f2bf(v.x); t[rr][c4 + 1] = f2bf(v.y);
        t[rr][c4 + 2] = f2bf(v.z); t[rr][c4 + 3] = f2bf(v.w);
    }
    __syncthreads();
    int kc = (threadIdx.x & 7) * 8;
    int rn = threadIdx.x >> 3;              // 0..31
#pragma unroll
    for (int i = 0; i < 2; ++i) {
        int nn = rn + i * 32;
        u16x8 o;
#pragma unroll
        for (int j = 0; j < 8; ++j) o[j] = t[kc + j][nn];
        *reinterpret_cast<u16x8*>(Wte + (size_t)(n0 + nn) * K + k0 + kc) = o;
    }
}

// ---------------- occupancy-first grouped GEMM (r7 core, frozen) ----------------
// BM=256, BN=128, BK=32, 512 thr, 8 waves (4M x 2N), per-wave 64x64.
// 2 blocks/CU = 16 waves/CU. Ring-3 slabs, depth-3 prefetch, counted vmcnt(6).
// LDS 72 KB: A 3x16K + B 3x8K. Swizzle (0 conflicts measured): store granule
// (tid&3)^((tid>>3)&3), read slot l4^((l15>>1)&3). Self-derived table from counts.
// NEW vs r7: pw folded into G1's silu epilogue ((w*h)@W2 == w*(h@W2), exact);
// G2 epilogue is a bare atomicAdd.
template<int N, int K, int SPLITK, bool IS_G1>
__global__ __launch_bounds__(512, 4) void moe_gemm15(
    const unsigned short* __restrict__ A,
    const unsigned short* __restrict__ Wt,
    const int* __restrict__ counts, const int* __restrict__ lists,
    const float* __restrict__ pw,
    unsigned short* __restrict__ Hout, float* __restrict__ Oout)
{
    constexpr int NT  = N / 128;
    constexpr int PAN = NT * SPLITK;
    constexpr int KS  = K / SPLITK;
    constexpr int NC  = KS / 32;
    static_assert(NC >= 4, "pipeline depth");

    __shared__ __attribute__((aligned(16))) char lds[73728];
    // A slot s: lds + s*16384 (256 rows x 64B); B slot s: lds + 49152 + s*8192

    int cnts[NE];
#pragma unroll
    for (int i = 0; i < NE; ++i) cnts[i] = counts[i];
    int ntl = 0;
#pragma unroll
    for (int i = 0; i < NE; ++i) ntl += (cnts[i] + 255) >> 8;

    int live = ntl * PAN;
    int orig = blockIdx.x;
    if (orig >= live) return;
    int q = live >> 3, r = live & 7;
    int xq = orig & 7, ib = orig >> 3;
    int work = (xq < r ? xq * (q + 1) : r * (q + 1) + (xq - r) * q) + ib;
    int rt    = work / PAN;                 // rt-major: neighbors share A-tile
    int panel = work - rt * PAN;
    int nt    = panel >> (SPLITK - 1);      // SPLITK is 1 or 2
    int sk    = panel & (SPLITK - 1);
    int koff  = sk * KS;

    // derive (e, slot0, off, cnt) from counts -- no offsets/table kernel
    int e = 0, tb = 0, off = 0, cnt = 0;
    {
        int ctb = 0, cob = 0; bool found = false;
#pragma unroll
        for (int i = 0; i < NE; ++i) {
            int ti = (cnts[i] + 255) >> 8;
            if (!found && rt < ctb + ti) { e = i; tb = ctb; off = cob; cnt = cnts[i]; found = true; }
            ctb += ti; cob += cnts[i];
        }
    }
    int slot0 = (rt - tb) << 8;
    int ntile = nt * 128;

    int tid  = threadIdx.x;
    int lane = tid & 63;
    int wid  = tid >> 6;
    int wm = wid >> 1;                  // 0..3
    int wn = wid & 1;                   // 0..1
    int l15 = lane & 15, l4 = lane >> 4;

    const unsigned short* Be = Wt + (size_t)e * N * K;

    // ---- staging offsets (elements). swizzle: granule ^= (row>>1)&3 ----
    int ssw = ((tid & 3) ^ ((tid >> 3) & 3)) * 8;
    unsigned aOff0, aOff1, bOff;
    {
        int r0 = tid >> 2;                  // 0..127
#pragma unroll
        for (int u = 0; u < 2; ++u) {
            int sl = slot0 + u * 128 + r0;
            unsigned grow;
            if (IS_G1) grow = (sl < cnt) ? (unsigned)(lists[e * T_TOK + sl] >> 1) : 0u;
            else       grow = (unsigned)(off + ((sl < cnt) ? sl : slot0));
            unsigned v = grow * (unsigned)K + (unsigned)(koff + ssw);
            if (u == 0) aOff0 = v; else aOff1 = v;
        }
        bOff = (unsigned)(ntile + r0) * (unsigned)K + (unsigned)(koff + ssw);
    }

    auto stage = [&](int s, int c) {
        int ko = c * 32;
        char* dA = lds + s * 16384 + tid * 16;
        char* dB = lds + 49152 + s * 8192 + tid * 16;
        GLDS16(A + aOff0 + ko, dA);
        GLDS16(A + aOff1 + ko, dA + 8192);
        GLDS16(Be + bOff + ko, dB);
    };

    // ---- fragment read bases (swizzled; row stride 64B) ----
    int swzb = (l4 ^ ((l15 >> 1) & 3)) * 16;
    int aRd = (wm * 64 + l15) * 64 + swzb;
    int bRd = (wn * 64 + l15) * 64 + swzb;

    f32x4 acc[4][4];
#pragma unroll
    for (int m = 0; m < 4; ++m)
#pragma unroll
        for (int n = 0; n < 4; ++n) acc[m][n] = (f32x4){0.f, 0.f, 0.f, 0.f};

    auto compute = [&](int s) {
        const char* Ab = lds + s * 16384;
        const char* Bb = lds + 49152 + s * 8192;
        s16x8 af[4];
#pragma unroll
        for (int m = 0; m < 4; ++m)
            af[m] = *reinterpret_cast<const s16x8*>(Ab + aRd + m * 1024);
        __builtin_amdgcn_s_setprio(1);
#pragma unroll
        for (int n = 0; n < 4; ++n) {
            s16x8 bf = *reinterpret_cast<const s16x8*>(Bb + bRd + n * 1024);
#pragma unroll
            for (int m = 0; m < 4; ++m)
                acc[m][n] = __builtin_amdgcn_mfma_f32_16x16x32_bf16(af[m], bf, acc[m][n], 0, 0, 0);
        }
        __builtin_amdgcn_s_setprio(0);
    };

    // ---- pipeline: 3-slot ring, depth-3 prefetch, counted vmcnt(6) ----
    stage(0, 0); stage(1, 1); stage(2, 2);
    int sslot = 0;
    for (int c = 0; c < NC; ++c) {
        if (c + 2 < NC)      waitvm<6>();   // chunk c done; c+1,c+2 in flight
        else if (c + 1 < NC) waitvm<3>();
        else                 waitvm<0>();
        BAR();
        compute(sslot);
        BAR();
        if (c + 3 < NC) stage(sslot, c + 3);
        sslot = (sslot == 2) ? 0 : sslot + 1;
    }

    // ---- epilogue: C/D col = lane&15, row = (lane>>4)*4 + rr ----
#pragma unroll
    for (int m = 0; m < 4; ++m) {
        int trow = wm * 64 + m * 16 + l4 * 4;
#pragma unroll
        for (int rr = 0; rr < 4; ++rr) {
            int slot = slot0 + trow + rr;
            if (slot >= cnt) continue;
            if (IS_G1) {
                int p = lists[e * T_TOK + slot];
                float w = pw[p];                 // gate folded into H (exact)
                unsigned short* hr = Hout + (size_t)(off + slot) * N;
#pragma unroll
                for (int n = 0; n < 4; ++n) {
                    int col = ntile + wn * 64 + n * 16 + l15;
                    float v = acc[m][n][rr];
                    float s = w * (v / (1.f + __expf(-v)));
                    hr[col] = f2bf(s);
                }
            } else {
                int p = lists[e * T_TOK + slot];
                float* orow = Oout + (size_t)(p >> 1) * DM;
#pragma unroll
                for (int n = 0; n < 4; ++n) {
                    int col = ntile + wn * 64 + n * 16 + l15;
                    atomicAdd(orow + col, acc[m][n][rr]);
                }
            }
        }
    }
}

// ================= fallback (round-1 validated fp32 path) =================
#define BMF 16
#define BFF 256
__global__ __launch_bounds__(256) void expert_gemm_f32(
    const float* __restrict__ x, const float* __restrict__ W1, const float* __restrict__ W2,
    const int* __restrict__ counts, const int* __restrict__ lists, const float* __restrict__ pw,
    float* __restrict__ out)
{
    int e    = blockIdx.y;
    int tile = blockIdx.x;
    int cnt  = counts[e];
    int start = tile * BMF;
    if (start >= cnt) return;

    __shared__ float xs[BMF][DM];
    __shared__ float hs[BMF][BFF];
    __shared__ int   toks[BMF];
    __shared__ float wgt[BMF];

    int tid = threadIdx.x;
    int nm  = cnt - start; if (nm > BMF) nm = BMF;

    if (tid < BMF) {
        if (tid < nm) {
            int p = lists[e * T_TOK + start + tid];
            toks[tid] = p >> 1;
            wgt[tid]  = pw[p];
        } else { toks[tid] = -1; wgt[tid] = 0.f; }
    }
    __syncthreads();
    for (int m = 0; m < BMF; ++m) {
        int t = toks[m];
        const float* xr = (t >= 0) ? (x + (size_t)t * DM) : nullptr;
        for (int i = tid; i < DM; i += 256) xs[m][i] = (t >= 0) ? xr[i] : 0.f;
    }
    __syncthreads();

    const float* W1e = W1 + (size_t)e * DM * DF;
    const float* W2e = W2 + (size_t)e * DF * DM;
    float acc[BMF][4];
#pragma unroll
    for (int m = 0; m < BMF; ++m)
#pragma unroll
        for (int c = 0; c < 4; ++c) acc[m][c] = 0.f;

    for (int fc = 0; fc < DF; fc += BFF) {
        float hacc[BMF];
#pragma unroll
        for (int m = 0; m < BMF; ++m) hacc[m] = 0.f;
        const float* w1col = W1e + fc + tid;
#pragma unroll 4
        for (int i = 0; i < DM; ++i) {
            float w1v = w1col[(size_t)i * DF];
#pragma unroll
            for (int m = 0; m < BMF; ++m) hacc[m] += xs[m][i] * w1v;
        }
        __syncthreads();
#pragma unroll
        for (int m = 0; m < BMF; ++m) {
            float v = hacc[m];
            hs[m][tid] = v / (1.f + __expf(-v));
        }
        __syncthreads();
        const float* w2base = W2e + (size_t)fc * DM + tid * 4;
        for (int f = 0; f < BFF; ++f) {
            float4 w2v = *reinterpret_cast<const float4*>(w2base + (size_t)f * DM);
#pragma unroll
            for (int m = 0; m < BMF; ++m) {
                float h = hs[m][f];
                acc[m][0] += h * w2v.x; acc[m][1] += h * w2v.y;
                acc[m][2] += h * w2v.z; acc[m][3] += h * w2v.w;
            }
        }
        __syncthreads();
    }
    int c0 = tid * 4;
#pragma unroll
    for (int m = 0; m < BMF; ++m) {
        int t = toks[m];
        if (t < 0) continue;
        float w = wgt[m];
        float* op = out + (size_t)t * DM + c0;
        atomicAdd(op + 0, w * acc[m][0]);
        atomicAdd(op + 1, w * acc[m][1]);
        atomicAdd(op + 2, w * acc[m][2]);
        atomicAdd(op + 3, w * acc[m][3]);
    }
}

// ================= launch =================
extern "C" void kernel_launch(void* const* d_in, const int* in_sizes, int n_in,
                              void* d_out, int out_size, void* d_ws, size_t ws_size,
                              hipStream_t stream)
{
    const float* x  = (const float*)d_in[0];
    const float* Wg = (const float*)d_in[1];
    const float* W1 = (const float*)d_in[2];
    const float* W2 = (const float*)d_in[3];
    float* out = (float*)d_out;

    char* ws = (char*)d_ws;
    int*      counts  = (int*)(ws + 0);
    int*      lists   = (int*)(ws + 2048);            // 256 KB
    float*    pw      = (float*)(ws + 2048 + 262144); // 64 KB

    const size_t o_xb  = 524288;
    const size_t sz_xb = (size_t)T_TOK * DM * 2;              // 16 MB
    const size_t o_w1t = o_xb + sz_xb;
    const size_t sz_w  = (size_t)NE * DM * DF * 2;            // 64 MB each
    const size_t o_w2t = o_w1t + sz_w;
    const size_t o_h   = o_w2t + sz_w;
    const size_t sz_h  = (size_t)(2 * T_TOK) * DF * 2;        // 134 MB
    const size_t NEEDED = o_h + sz_h;

    bool fast = (ws_size >= NEEDED);
    unsigned short* xb  = fast ? (unsigned short*)(ws + o_xb)  : nullptr;
    unsigned short* w1t = fast ? (unsigned short*)(ws + o_w1t) : nullptr;
    unsigned short* w2t = fast ? (unsigned short*)(ws + o_w2t) : nullptr;

    hipMemsetAsync(counts, 0, 64, stream);
    // one launch: route (2048 blocks) + W1 transpose (8192) + W2 transpose (8192)
    prep_kernel<<<fast ? 18432 : 2048, 256, 0, stream>>>(
        x, Wg, W1, W2, counts, lists, pw, xb, w1t, w2t, out);

    if (fast) {
        unsigned short* H = (unsigned short*)(ws + o_h);
        // G1: [cnt x 1024] @ W1t -> silu*gate -> H (bf16), 256x128 tiles
        moe_gemm15<DF, DM, 1, true><<<dim3(MAXT * 32), 512, 0, stream>>>(
            xb, w1t, counts, lists, pw, H, nullptr);
        // G2: H @ W2t -> atomic-add into out (gate pre-applied), split-K 2
        moe_gemm15<DM, DF, 2, false><<<dim3(MAXT * 16), 512, 0, stream>>>(
            H, w2t, counts, lists, pw, nullptr, out);
    } else {
        dim3 grid(T_TOK / BMF, NE);
        expert_gemm_f32<<<grid, 256, 0, stream>>>(x, W1, W2, counts, lists, pw, out);
    }
}